// Round 2
// baseline (4902.362 us; speedup 1.0000x reference)
//
#include <hip/hip_runtime.h>

// 3-layer LSTM (H=64, B=512, T=2048) + linear head (OUT=11), all fp32.
// One block (4 waves) per batch element; thread k owns gate row k.
// Weights in VGPRs; h/x broadcast via per-wave LDS; one barrier per step.
//
// In-place safety (layers 1,2: x_in aliases hs_out):
//   - each wave's load of x[t+1] is consumed (vmcnt forced by the xbuf
//     ds_write publish) BEFORE that wave reaches barrier #(t+1);
//   - wave 0 stores h[t+1] only AFTER passing barrier #(t+1);
//   => every read of an address completes before its only write.

namespace {
constexpr int kH   = 64;
constexpr int kT   = 2048;
constexpr int kB   = 512;
constexpr int kOut = 11;
}

__device__ __forceinline__ float fast_rcp(float x) { return __builtin_amdgcn_rcpf(x); }

__device__ __forceinline__ float sigmoid_f(float x) {
    // |preact| is bounded (weights ~U(-1/8,1/8), inputs bounded): no overflow.
    return fast_rcp(1.0f + __expf(-x));
}

__device__ __forceinline__ float tanh_f(float x) {
    // Valid for any |x| (c can drift over 2048 steps): e in (0,1].
    const float ax = fabsf(x);
    const float e  = __expf(-2.0f * ax);
    const float t  = (1.0f - e) * fast_rcp(1.0f + e);
    return copysignf(t, x);
}

template <int D_IN>
__global__ __launch_bounds__(256, 2)
void lstm_layer_kernel(const float* x_in,            // may alias hs_out
                       const float* __restrict__ Wih,
                       const float* __restrict__ Whh,
                       const float* __restrict__ bih,
                       const float* __restrict__ bhh,
                       float* hs_out)
{
    const int b    = blockIdx.x;
    const int k    = threadIdx.x;   // gate row 0..255 (i,f,g,o blocks of 64)
    const int wave = k >> 6;        // == gate type (wave-uniform activation)
    const int lane = k & 63;        // == hidden unit for the update phase

    __shared__ float hbuf[4][kH];      // per-wave h broadcast buffer
    __shared__ float xbuf[4][D_IN];    // per-wave x broadcast buffer
    __shared__ float gates[2][4 * kH]; // t-parity double-buffered activations

    // ---- load this thread's weight rows into registers (~70 VGPRs) ----
    float wh[kH];
#pragma unroll
    for (int j = 0; j < kH; j += 4) {
        const float4 v = *reinterpret_cast<const float4*>(&Whh[k * kH + j]);
        wh[j] = v.x; wh[j + 1] = v.y; wh[j + 2] = v.z; wh[j + 3] = v.w;
    }
    float wx[D_IN];
    if constexpr (D_IN == 2) {
        const float2 v = *reinterpret_cast<const float2*>(&Wih[k * 2]);
        wx[0] = v.x; wx[1] = v.y;
    } else {
#pragma unroll
        for (int j = 0; j < D_IN; j += 4) {
            const float4 v = *reinterpret_cast<const float4*>(&Wih[k * D_IN + j]);
            wx[j] = v.x; wx[j + 1] = v.y; wx[j + 2] = v.z; wx[j + 3] = v.w;
        }
    }
    const float bias = bih[k] + bhh[k];

    hbuf[wave][lane] = 0.0f;   // h0 = 0 (own-wave buffer: no barrier needed)
    float c = 0.0f;            // lane's unit-c, replicated per wave

    const float* xb = x_in   + (size_t)b * kT * D_IN;
    float*       hb = hs_out + (size_t)b * kT * kH;

    float xreg = 0.0f;
    if (lane < D_IN) xreg = xb[lane];   // prefetch x_0

    for (int t = 0; t < kT; ++t) {
        // publish x_t (ds_write consumes prefetch -> vmcnt wait before barrier)
        if (lane < D_IN) xbuf[wave][lane] = xreg;
        // prefetch x_{t+1} (clamped; last iteration re-reads x_{T-1}, unused)
        const int tn = (t + 1 < kT) ? (t + 1) : t;
        if (lane < D_IN) xreg = xb[(size_t)tn * D_IN + lane];

        // ---- gate preactivation: bias + Wih x_t + Whh h_{t-1} ----
        // 4 independent accumulator chains: dependent-issue spacing ~8 cyc
        // (wave64, SIMD-32) > 4-cyc FMA latency, even at 2 waves/SIMD.
        float a0 = bias, a1 = 0.0f, a2 = 0.0f, a3 = 0.0f;
        if constexpr (D_IN == 2) {
            a0 = fmaf(xbuf[wave][0], wx[0], a0);
            a1 = fmaf(xbuf[wave][1], wx[1], a1);
        } else {
#pragma unroll
            for (int j = 0; j < D_IN; j += 4) {
                const float4 v = *reinterpret_cast<const float4*>(&xbuf[wave][j]);
                a0 = fmaf(v.x, wx[j + 0], a0);
                a1 = fmaf(v.y, wx[j + 1], a1);
                a2 = fmaf(v.z, wx[j + 2], a2);
                a3 = fmaf(v.w, wx[j + 3], a3);
            }
        }
#pragma unroll
        for (int j = 0; j < kH; j += 4) {
            const float4 v = *reinterpret_cast<const float4*>(&hbuf[wave][j]);
            a0 = fmaf(v.x, wh[j + 0], a0);
            a1 = fmaf(v.y, wh[j + 1], a1);
            a2 = fmaf(v.z, wh[j + 2], a2);
            a3 = fmaf(v.w, wh[j + 3], a3);
        }
        const float pre = (a0 + a1) + (a2 + a3);
        const float act = (wave == 2) ? tanh_f(pre) : sigmoid_f(pre);
        gates[t & 1][k] = act;
        __syncthreads();

        // ---- c/h update, redundant per wave (lane n owns unit n) ----
        const float gi = gates[t & 1][lane];
        const float gf = gates[t & 1][lane + 64];
        const float gg = gates[t & 1][lane + 128];
        const float go = gates[t & 1][lane + 192];
        c = fmaf(gf, c, gi * gg);
        const float h = go * tanh_f(c);
        hbuf[wave][lane] = h;                    // own-wave buffer: no barrier
        if (wave == 0) hb[(size_t)t * kH + lane] = h;
    }
}

__global__ void out_proj_kernel(const float* __restrict__ hs,
                                const float* __restrict__ Wout,
                                const float* __restrict__ bout,
                                float* __restrict__ out)
{
    const int b    = blockIdx.x;
    const int lane = threadIdx.x;  // 64
    const float h = hs[(size_t)b * kT * kH + (size_t)(kT - 1) * kH + lane];
#pragma unroll
    for (int o = 0; o < kOut; ++o) {
        float p = h * Wout[o * kH + lane];
#pragma unroll
        for (int s = 32; s > 0; s >>= 1) p += __shfl_xor(p, s, 64);
        if (lane == 0) out[b * kOut + o] = p + bout[o];
    }
}

extern "C" void kernel_launch(void* const* d_in, const int* in_sizes, int n_in,
                              void* d_out, int out_size, void* d_ws, size_t ws_size,
                              hipStream_t stream)
{
    const float* x    = (const float*)d_in[0];
    const float* Wih0 = (const float*)d_in[1];
    const float* Whh0 = (const float*)d_in[2];
    const float* bih0 = (const float*)d_in[3];
    const float* bhh0 = (const float*)d_in[4];
    const float* Wih1 = (const float*)d_in[5];
    const float* Whh1 = (const float*)d_in[6];
    const float* bih1 = (const float*)d_in[7];
    const float* bhh1 = (const float*)d_in[8];
    const float* Wih2 = (const float*)d_in[9];
    const float* Whh2 = (const float*)d_in[10];
    const float* bih2 = (const float*)d_in[11];
    const float* bhh2 = (const float*)d_in[12];
    const float* Wout = (const float*)d_in[13];
    const float* bout = (const float*)d_in[14];
    (void)in_sizes; (void)n_in; (void)out_size; (void)ws_size;

    // hs buffer: B*T*H fp32 = 256 MiB in workspace; layers 1,2 run in-place.
    float* hs = (float*)d_ws;

    lstm_layer_kernel<2 ><<<kB, 256, 0, stream>>>(x,  Wih0, Whh0, bih0, bhh0, hs);
    lstm_layer_kernel<64><<<kB, 256, 0, stream>>>(hs, Wih1, Whh1, bih1, bhh1, hs);
    lstm_layer_kernel<64><<<kB, 256, 0, stream>>>(hs, Whh2 ? Wih2 : Wih2, Whh2, bih2, bhh2, hs);
    out_proj_kernel<<<kB, 64, 0, stream>>>(hs, Wout, bout, (float*)d_out);
}

// Round 4
// 4614.591 us; speedup vs baseline: 1.0624x; 1.0624x over previous
//
#include <hip/hip_runtime.h>

// 3-layer LSTM (H=64, B=512, T=2048) + linear head (OUT=11), all fp32.
// One block (4 waves) per batch element; thread k owns gate row k.
// Weights in VGPRs; h/x broadcast via per-wave LDS; one barrier per step.
//
// Round-2 fixes (unmeasured in r2 — broker timeout — resubmitted in r3):
//  * amdgpu_waves_per_eu(2,2): pin 2 waves/EU -> 256-VGPR budget, stops the
//    allocator from rematerializing weight loads inside the t-loop (r1 had
//    VGPR_Count=84 -> weights re-read from L2 every step, 2285 cyc/step).
//  * weight pointers NOT __restrict__: in-loop stores to hs_out may alias
//    them, making in-loop reload illegal -> weights must stay in VGPRs.
//  * layer 2 stores only h[T-1] (head needs only the last timestep); it goes
//    into the t=0 slot of its row (read-complete since step 0, same block).
//
// In-place safety (layers 1,2: x_in aliases hs_out):
//   - each wave's load of x[t+1] is consumed (vmcnt forced by the xbuf
//     ds_write publish) BEFORE that wave reaches barrier #(t+1);
//   - wave 0 stores h[t+1] only AFTER passing barrier #(t+1).

namespace {
constexpr int kH   = 64;
constexpr int kT   = 2048;
constexpr int kB   = 512;
constexpr int kOut = 11;
}

__device__ __forceinline__ float fast_rcp(float x) { return __builtin_amdgcn_rcpf(x); }

__device__ __forceinline__ float sigmoid_f(float x) {
    return fast_rcp(1.0f + __expf(-x));
}

__device__ __forceinline__ float tanh_f(float x) {
    // Valid for any |x| (c can drift over 2048 steps): e in (0,1].
    const float ax = fabsf(x);
    const float e  = __expf(-2.0f * ax);
    const float t  = (1.0f - e) * fast_rcp(1.0f + e);
    return copysignf(t, x);
}

template <int D_IN, bool STORE_ALL>
__global__
__attribute__((amdgpu_flat_work_group_size(256, 256), amdgpu_waves_per_eu(2, 2)))
void lstm_layer_kernel(const float* x_in,   // may alias hs_out (layers 1,2)
                       const float* Wih,    // no __restrict__: anti-remat
                       const float* Whh,    // no __restrict__: anti-remat
                       const float* bih,
                       const float* bhh,
                       float* hs_out)
{
    const int b    = blockIdx.x;
    const int k    = threadIdx.x;   // gate row 0..255 (i,f,g,o blocks of 64)
    const int wave = k >> 6;        // == gate type (wave-uniform activation)
    const int lane = k & 63;        // == hidden unit for the update phase

    __shared__ float hbuf[4][kH];      // per-wave h broadcast buffer
    __shared__ float xbuf[4][D_IN];    // per-wave x broadcast buffer
    __shared__ float gates[2][4 * kH]; // t-parity double-buffered activations

    // ---- weight rows -> VGPRs (float4-packed, fully unrolled indices) ----
    float4 wh4[16];
#pragma unroll
    for (int j = 0; j < 16; ++j)
        wh4[j] = *reinterpret_cast<const float4*>(&Whh[k * kH + j * 4]);

    float4 wx4[D_IN / 4 > 0 ? D_IN / 4 : 1];
    float2 wx2;
    if constexpr (D_IN == 2) {
        wx2 = *reinterpret_cast<const float2*>(&Wih[k * 2]);
    } else {
#pragma unroll
        for (int j = 0; j < D_IN / 4; ++j)
            wx4[j] = *reinterpret_cast<const float4*>(&Wih[k * D_IN + j * 4]);
    }
    const float bias = bih[k] + bhh[k];

    hbuf[wave][lane] = 0.0f;   // h0 = 0 (own-wave buffer: no barrier needed)
    float c = 0.0f;            // lane's unit-c, replicated per wave

    const float* xb = x_in   + (size_t)b * kT * D_IN;
    float*       hb = hs_out + (size_t)b * kT * kH;

    float xreg = 0.0f;
    if (lane < D_IN) xreg = xb[lane];   // prefetch x_0

    for (int t = 0; t < kT; ++t) {
        // publish x_t (ds_write consumes prefetch -> vmcnt wait before barrier)
        if (lane < D_IN) xbuf[wave][lane] = xreg;
        // prefetch x_{t+1} (clamped; last iteration re-reads x_{T-1}, unused)
        const int tn = (t + 1 < kT) ? (t + 1) : t;
        if (lane < D_IN) xreg = xb[(size_t)tn * D_IN + lane];

        // ---- gate preactivation: bias + Wih x_t + Whh h_{t-1} ----
        // 4 independent accumulator chains: dependent-issue spacing ~8 cyc
        // (wave64, SIMD-32) > ~4-cyc FMA latency.
        float a0 = bias, a1 = 0.0f, a2 = 0.0f, a3 = 0.0f;
        if constexpr (D_IN == 2) {
            a0 = fmaf(xbuf[wave][0], wx2.x, a0);
            a1 = fmaf(xbuf[wave][1], wx2.y, a1);
        } else {
#pragma unroll
            for (int j = 0; j < D_IN / 4; ++j) {
                const float4 v = *reinterpret_cast<const float4*>(&xbuf[wave][j * 4]);
                a0 = fmaf(v.x, wx4[j].x, a0);
                a1 = fmaf(v.y, wx4[j].y, a1);
                a2 = fmaf(v.z, wx4[j].z, a2);
                a3 = fmaf(v.w, wx4[j].w, a3);
            }
        }
#pragma unroll
        for (int j = 0; j < 16; ++j) {
            const float4 v = *reinterpret_cast<const float4*>(&hbuf[wave][j * 4]);
            a0 = fmaf(v.x, wh4[j].x, a0);
            a1 = fmaf(v.y, wh4[j].y, a1);
            a2 = fmaf(v.z, wh4[j].z, a2);
            a3 = fmaf(v.w, wh4[j].w, a3);
        }
        const float pre = (a0 + a1) + (a2 + a3);
        const float act = (wave == 2) ? tanh_f(pre) : sigmoid_f(pre);
        gates[t & 1][k] = act;
        __syncthreads();

        // ---- c/h update, redundant per wave (lane n owns unit n) ----
        const float gi = gates[t & 1][lane];
        const float gf = gates[t & 1][lane + 64];
        const float gg = gates[t & 1][lane + 128];
        const float go = gates[t & 1][lane + 192];
        c = fmaf(gf, c, gi * gg);
        const float h = go * tanh_f(c);
        hbuf[wave][lane] = h;                    // own-wave buffer: no barrier
        if constexpr (STORE_ALL) {
            if (wave == 0) hb[(size_t)t * kH + lane] = h;
        } else {
            // only h[T-1] is consumed downstream; park it in the t=0 slot
            // (that address was read at step 0 by this same block only).
            if (wave == 0 && t == kT - 1) hb[lane] = h;
        }
    }
}

__global__ void out_proj_kernel(const float* __restrict__ hlast, // [B][kH] at row stride kT*kH
                                const float* __restrict__ Wout,
                                const float* __restrict__ bout,
                                float* __restrict__ out)
{
    const int b    = blockIdx.x;
    const int lane = threadIdx.x;  // 64
    const float h = hlast[(size_t)b * kT * kH + lane];
#pragma unroll
    for (int o = 0; o < kOut; ++o) {
        float p = h * Wout[o * kH + lane];
#pragma unroll
        for (int s = 32; s > 0; s >>= 1) p += __shfl_xor(p, s, 64);
        if (lane == 0) out[b * kOut + o] = p + bout[o];
    }
}

extern "C" void kernel_launch(void* const* d_in, const int* in_sizes, int n_in,
                              void* d_out, int out_size, void* d_ws, size_t ws_size,
                              hipStream_t stream)
{
    const float* x    = (const float*)d_in[0];
    const float* Wih0 = (const float*)d_in[1];
    const float* Whh0 = (const float*)d_in[2];
    const float* bih0 = (const float*)d_in[3];
    const float* bhh0 = (const float*)d_in[4];
    const float* Wih1 = (const float*)d_in[5];
    const float* Whh1 = (const float*)d_in[6];
    const float* bih1 = (const float*)d_in[7];
    const float* bhh1 = (const float*)d_in[8];
    const float* Wih2 = (const float*)d_in[9];
    const float* Whh2 = (const float*)d_in[10];
    const float* bih2 = (const float*)d_in[11];
    const float* bhh2 = (const float*)d_in[12];
    const float* Wout = (const float*)d_in[13];
    const float* bout = (const float*)d_in[14];
    (void)in_sizes; (void)n_in; (void)out_size; (void)ws_size;

    // hs buffer: B*T*H fp32 = 256 MiB in workspace; layers 1,2 run in-place.
    float* hs = (float*)d_ws;

    lstm_layer_kernel<2,  true ><<<kB, 256, 0, stream>>>(x,  Wih0, Whh0, bih0, bhh0, hs);
    lstm_layer_kernel<64, true ><<<kB, 256, 0, stream>>>(hs, Wih1, Whh1, bih1, bhh1, hs);
    lstm_layer_kernel<64, false><<<kB, 256, 0, stream>>>(hs, Wih2, Whh2, bih2, bhh2, hs);
    out_proj_kernel<<<kB, 64, 0, stream>>>(hs, Wout, bout, (float*)d_out);
}